// Round 14
// baseline (177.613 us; speedup 1.0000x reference)
//
#include <hip/hip_runtime.h>
#include <hip/hip_fp16.h>

#define NN 50000
#define BN_EPS_C 1e-5f
#define SCAN_CHUNK 512
#define NSB ((NN + SCAN_CHUNK - 1) / SCAN_CHUNK)  // 98
#define CONVB 256  // conversion blocks in prephist_k

__device__ inline unsigned short f2h_bits(float f) {
  __half h = __float2half_rn(f);
  return *reinterpret_cast<unsigned short*>(&h);
}
__device__ inline float h_bits2f(unsigned short b) {
  __half h;
  *reinterpret_cast<unsigned short*>(&h) = b;
  return __half2float(h);
}
__device__ inline unsigned pack2(float a, float b) {
  __half2 h = __floats2half2_rn(a, b);
  return *reinterpret_cast<unsigned*>(&h);
}

// ---- merged: {W transpose + x->fp16} blocks || {histogram + rank} blocks ----
// counts/sums pre-zeroed by hipMemsetAsync.
__global__ __launch_bounds__(256) void prephist_k(const float* __restrict__ x,
                                                  const float* __restrict__ W1,
                                                  const float* __restrict__ W2,
                                                  const int* __restrict__ dst,
                                                  int* __restrict__ counts,
                                                  int* __restrict__ rank,
                                                  float* __restrict__ W1t,
                                                  float* __restrict__ W2t,
                                                  unsigned short* __restrict__ xh,
                                                  int E) {
  int tid = threadIdx.x;
  if (blockIdx.x < CONVB) {
    int gid = blockIdx.x * 256 + tid;
    int stride = CONVB * 256;
    for (int i = gid; i < 4096; i += stride) {
      int f = i >> 6, k = i & 63;
      W1t[k * 64 + f] = W1[i];
      W2t[k * 64 + f] = W2[i];
    }
    const float4* x4 = (const float4*)x;
    uint2* xh2 = (uint2*)xh;
    for (int i = gid; i < NN * 16; i += stride) {
      float4 v = x4[i];
      uint2 u;
      u.x = pack2(v.x, v.y);
      u.y = pack2(v.z, v.w);
      xh2[i] = u;
    }
  } else {
    int t = (blockIdx.x - CONVB) * 256 + tid;
    int e = t * 8;
    if (e + 7 < E) {
      int4 dA = *(const int4*)(dst + e);
      int4 dB = *(const int4*)(dst + e + 4);
      int4 rA, rB;
      rA.x = atomicAdd(&counts[dA.x], 1);
      rA.y = atomicAdd(&counts[dA.y], 1);
      rA.z = atomicAdd(&counts[dA.z], 1);
      rA.w = atomicAdd(&counts[dA.w], 1);
      rB.x = atomicAdd(&counts[dB.x], 1);
      rB.y = atomicAdd(&counts[dB.y], 1);
      rB.z = atomicAdd(&counts[dB.z], 1);
      rB.w = atomicAdd(&counts[dB.w], 1);
      *(int4*)(rank + e) = rA;
      *(int4*)(rank + e + 4) = rB;
    } else {
      for (; e < E; ++e) rank[e] = atomicAdd(&counts[dst[e]], 1);
    }
  }
}

// ---- single scan kernel: block b reduces counts[0..b*512) for its base,
// then local exclusive scan of its 512-chunk -> offs ----
__global__ __launch_bounds__(256) void scan_k(const int* __restrict__ counts,
                                              int* __restrict__ offs) {
  __shared__ int s[256];
  __shared__ int basev;
  int b = blockIdx.x, tid = threadIdx.x;
  int lim = b * SCAN_CHUNK;
  int acc = 0;
  for (int i = tid; i < lim; i += 256) acc += counts[i];
  s[tid] = acc;
  __syncthreads();
  for (int st = 128; st > 0; st >>= 1) {
    if (tid < st) s[tid] += s[tid + st];
    __syncthreads();
  }
  if (tid == 0) basev = s[0];
  __syncthreads();
  int base = basev;
  __syncthreads();  // s reusable
  int i0 = lim + 2 * tid;
  int c0 = (i0 < NN) ? counts[i0] : 0;
  int c1 = (i0 + 1 < NN) ? counts[i0 + 1] : 0;
  int tsum = c0 + c1;
  s[tid] = tsum;
  __syncthreads();
  for (int off = 1; off < 256; off <<= 1) {
    int t = (tid >= off) ? s[tid - off] : 0;
    __syncthreads();
    s[tid] += t;
    __syncthreads();
  }
  int pre = base + s[tid] - tsum;
  if (i0 < NN) offs[i0] = pre;
  if (i0 + 1 < NN) offs[i0 + 1] = pre + c0;
}

// ---- atomic-free sorted edge build: sorted[offs[d]+rank[e]] = {w:fp16|src:u16} ----
__global__ __launch_bounds__(256) void sort_k(const int* __restrict__ dst,
                                              const int* __restrict__ rank,
                                              const int* __restrict__ srcv,
                                              const float* __restrict__ ew,
                                              const int* __restrict__ offs,
                                              unsigned* __restrict__ sorted, int E) {
  int t = blockIdx.x * 256 + threadIdx.x;
  int e = t * 8;
  if (e + 7 < E) {
    int4 dA = *(const int4*)(dst + e);
    int4 dB = *(const int4*)(dst + e + 4);
    int4 rA = *(const int4*)(rank + e);
    int4 rB = *(const int4*)(rank + e + 4);
    int4 sA = *(const int4*)(srcv + e);
    int4 sB = *(const int4*)(srcv + e + 4);
    float4 wA = *(const float4*)(ew + e);
    float4 wB = *(const float4*)(ew + e + 4);
    sorted[offs[dA.x] + rA.x] = (unsigned)sA.x | ((unsigned)f2h_bits(wA.x) << 16);
    sorted[offs[dA.y] + rA.y] = (unsigned)sA.y | ((unsigned)f2h_bits(wA.y) << 16);
    sorted[offs[dA.z] + rA.z] = (unsigned)sA.z | ((unsigned)f2h_bits(wA.z) << 16);
    sorted[offs[dA.w] + rA.w] = (unsigned)sA.w | ((unsigned)f2h_bits(wA.w) << 16);
    sorted[offs[dB.x] + rB.x] = (unsigned)sB.x | ((unsigned)f2h_bits(wB.x) << 16);
    sorted[offs[dB.y] + rB.y] = (unsigned)sB.y | ((unsigned)f2h_bits(wB.y) << 16);
    sorted[offs[dB.z] + rB.z] = (unsigned)sB.z | ((unsigned)f2h_bits(wB.z) << 16);
    sorted[offs[dB.w] + rB.w] = (unsigned)sB.w | ((unsigned)f2h_bits(wB.w) << 16);
  } else {
    for (; e < E; ++e) {
      unsigned v = (unsigned)srcv[e] | ((unsigned)f2h_bits(ew[e]) << 16);
      sorted[offs[dst[e]] + rank[e]] = v;
    }
  }
}

// ------- fp16 accumulate: 8 halves (uint4) -> 8 f32 accumulators -------
__device__ inline void acc8(float* a, uint4 q, float wgt) {
  float2 f;
  f = __half22float2(*(const __half2*)&q.x);
  a[0] = fmaf(wgt, f.x, a[0]); a[1] = fmaf(wgt, f.y, a[1]);
  f = __half22float2(*(const __half2*)&q.y);
  a[2] = fmaf(wgt, f.x, a[2]); a[3] = fmaf(wgt, f.y, a[3]);
  f = __half22float2(*(const __half2*)&q.z);
  a[4] = fmaf(wgt, f.x, a[4]); a[5] = fmaf(wgt, f.y, a[5]);
  f = __half22float2(*(const __half2*)&q.w);
  a[6] = fmaf(wgt, f.x, a[6]); a[7] = fmaf(wgt, f.y, a[7]);
}

// ------- overflow tail for deg > 64 (rare) -------
__device__ inline void ovf8(float* a, const uint4* __restrict__ xh4,
                            const unsigned* __restrict__ sorted,
                            int off, int cnt, int lane, int es, int fo) {
  for (int b = 64; b < cnt; b += 64) {
    int take = min(64, cnt - b);
    unsigned m = 0;
    if (lane < take) m = sorted[off + b + lane];
    int nb = (take + 7) >> 3;
    for (int t = 0; t < nb; ++t) {
      int i0 = t * 8 + es;
      unsigned v = __shfl((int)m, i0);
      int s = (int)(v & 0xFFFFu);
      float wgt = h_bits2f((unsigned short)(v >> 16));
      uint4 q = xh4[s * 8 + fo];
      acc8(a, q, wgt);
    }
  }
}

// ---------------- gather: yh[n] = fp16( (1+eps)*xh[n] + sum_e w_e*xh[src_e] ) ----
// 8 nodes/wave, 16 independent 16B loads in flight. Residual xh row loaded
// early (lane (es,fo) covers node nbase+es octet fo). fp16 stage + 1KB store.
__global__ __launch_bounds__(256) void gather_k(const unsigned short* __restrict__ xh,
                                                const unsigned* __restrict__ sorted,
                                                const int* __restrict__ offs,
                                                const int* __restrict__ counts,
                                                const float* __restrict__ eps,
                                                unsigned short* __restrict__ yh) {
  __shared__ uint4 stage[4][8][8];  // [wave][node][octet] fp16x8, 4KB
  int tid = threadIdx.x;
  int lane = tid & 63;
  int wv = tid >> 6;
  int es = lane >> 3, fo = lane & 7;
  int nbase = (blockIdx.x * 4 + wv) * 8;
  if (nbase >= NN) return;
  const float c1 = 1.0f + eps[0];
  const uint4* xh4 = (const uint4*)xh;
  uint4* yh4 = (uint4*)yh;

  int offv[8], cntv[8];
  unsigned mv[8];
#pragma unroll
  for (int i = 0; i < 8; ++i) {
    int node = nbase + i;
    bool vld = node < NN;
    offv[i] = vld ? offs[node] : 0;
    cntv[i] = vld ? counts[node] : 0;
  }
  // early residual load: lane (es,fo) holds node nbase+es, octet fo
  int rnode = min(nbase + es, NN - 1);
  uint4 xq_r = xh4[rnode * 8 + fo];
#pragma unroll
  for (int i = 0; i < 8; ++i) {
    int tk = min(cntv[i], 64);
    mv[i] = (lane < tk) ? sorted[offv[i] + lane] : 0u;
  }
  float acc[8][8] = {};
  int nbM = 0;
#pragma unroll
  for (int i = 0; i < 8; ++i) nbM = max(nbM, (min(cntv[i], 64) + 7) >> 3);

  for (int t = 0; t < nbM; t += 2) {
    int i0 = t * 8 + es;  // <= 55 (t <= 6)
    int i1 = i0 + 8;      // <= 63; lanes past tk hold m=0 -> w=0
    unsigned e0[8], e1[8];
    uint4 q0[8], q1[8];
#pragma unroll
    for (int i = 0; i < 8; ++i) {
      e0[i] = (unsigned)__shfl((int)mv[i], i0);
      e1[i] = (unsigned)__shfl((int)mv[i], i1);
    }
#pragma unroll
    for (int i = 0; i < 8; ++i) q0[i] = xh4[(int)(e0[i] & 0xFFFFu) * 8 + fo];
#pragma unroll
    for (int i = 0; i < 8; ++i) q1[i] = xh4[(int)(e1[i] & 0xFFFFu) * 8 + fo];
#pragma unroll
    for (int i = 0; i < 8; ++i)
      acc8(acc[i], q0[i], h_bits2f((unsigned short)(e0[i] >> 16)));
#pragma unroll
    for (int i = 0; i < 8; ++i)
      acc8(acc[i], q1[i], h_bits2f((unsigned short)(e1[i] >> 16)));
  }
#pragma unroll
  for (int i = 0; i < 8; ++i)
    if (cntv[i] > 64) ovf8(acc[i], xh4, sorted, offv[i], cntv[i], lane, es, fo);

  // reduce across es (lane bits 3,4,5)
#pragma unroll
  for (int i = 0; i < 8; ++i)
#pragma unroll
    for (int j = 0; j < 8; ++j) {
      acc[i][j] += __shfl_xor(acc[i][j], 8);
      acc[i][j] += __shfl_xor(acc[i][j], 16);
      acc[i][j] += __shfl_xor(acc[i][j], 32);
    }
  // stage: es group i finalizes node nbase+i (residual + fp16 pack)
#pragma unroll
  for (int i = 0; i < 8; ++i) {
    if (es == i) {
      float2 f;
      float r[8];
      f = __half22float2(*(const __half2*)&xq_r.x); r[0] = f.x; r[1] = f.y;
      f = __half22float2(*(const __half2*)&xq_r.y); r[2] = f.x; r[3] = f.y;
      f = __half22float2(*(const __half2*)&xq_r.z); r[4] = f.x; r[5] = f.y;
      f = __half22float2(*(const __half2*)&xq_r.w); r[6] = f.x; r[7] = f.y;
      uint4 u;
      u.x = pack2(fmaf(c1, r[0], acc[i][0]), fmaf(c1, r[1], acc[i][1]));
      u.y = pack2(fmaf(c1, r[2], acc[i][2]), fmaf(c1, r[3], acc[i][3]));
      u.z = pack2(fmaf(c1, r[4], acc[i][4]), fmaf(c1, r[5], acc[i][5]));
      u.w = pack2(fmaf(c1, r[6], acc[i][6]), fmaf(c1, r[7], acc[i][7]));
      stage[wv][i][fo] = u;
    }
  }
  __builtin_amdgcn_wave_barrier();  // intra-wave ordering of DS ops
  // dense store: lane l -> node nbase+(l>>3), octet l&7 : 1KB/wave contiguous
  {
    int node = nbase + (lane >> 3);
    if (node < NN) yh4[node * 8 + (lane & 7)] = stage[wv][lane >> 3][lane & 7];
  }
}

// ---------------- MLP1(relu) + MLP2 + BN partials from yh (fp16) ----------------
__global__ __launch_bounds__(256) void mlp_k(const unsigned short* __restrict__ yh,
                                             const float* __restrict__ W1t,
                                             const float* __restrict__ W2t,
                                             const float* __restrict__ b1,
                                             const float* __restrict__ b2,
                                             float* __restrict__ out,
                                             float* __restrict__ sums) {
  __shared__ float hT[64][66];   // [k][local node]
  __shared__ float WA[64][64];
  int tid = threadIdx.x;
  int tile0 = blockIdx.x * 64;
  for (int i = tid; i < 4096; i += 256) ((float*)WA)[i] = W1t[i];
  const uint2* yh2 = (const uint2*)yh;
  for (int i = tid; i < 1024; i += 256) {
    int nl = i >> 4, hq = i & 15;
    int node = tile0 + nl;
    uint2 v = {0, 0};
    if (node < NN) v = yh2[node * 16 + hq];
    float2 a = __half22float2(*(const __half2*)&v.x);
    float2 b = __half22float2(*(const __half2*)&v.y);
    hT[4 * hq + 0][nl] = a.x; hT[4 * hq + 1][nl] = a.y;
    hT[4 * hq + 2][nl] = b.x; hT[4 * hq + 3][nl] = b.y;
  }
  __syncthreads();

  int fg = tid & 15, ng = tid >> 4;
  int f0 = fg * 4, n0 = ng * 4;
  float4 bv = *(const float4*)(b1 + f0);
  float o[4][4];
#pragma unroll
  for (int n = 0; n < 4; ++n) {
    o[n][0] = bv.x; o[n][1] = bv.y; o[n][2] = bv.z; o[n][3] = bv.w;
  }
#pragma unroll 8
  for (int k = 0; k < 64; ++k) {
    float2 iA = *(const float2*)&hT[k][n0];
    float2 iB = *(const float2*)&hT[k][n0 + 2];
    float4 w4 = *(const float4*)&WA[k][f0];
    float in[4] = {iA.x, iA.y, iB.x, iB.y};
    float ww[4] = {w4.x, w4.y, w4.z, w4.w};
#pragma unroll
    for (int n = 0; n < 4; ++n)
#pragma unroll
      for (int j = 0; j < 4; ++j) o[n][j] = fmaf(in[n], ww[j], o[n][j]);
  }
#pragma unroll
  for (int n = 0; n < 4; ++n)
#pragma unroll
    for (int j = 0; j < 4; ++j) o[n][j] = fmaxf(o[n][j], 0.f);

  __syncthreads();  // all GEMM1 reads done
#pragma unroll
  for (int j = 0; j < 4; ++j) {
    float2 vA = {o[0][j], o[1][j]}, vB = {o[2][j], o[3][j]};
    *(float2*)&hT[f0 + j][n0] = vA;
    *(float2*)&hT[f0 + j][n0 + 2] = vB;
  }
  for (int i = tid; i < 4096; i += 256) ((float*)WA)[i] = W2t[i];
  __syncthreads();

  float4 bv2 = *(const float4*)(b2 + f0);
  float o2[4][4];
#pragma unroll
  for (int n = 0; n < 4; ++n) {
    o2[n][0] = bv2.x; o2[n][1] = bv2.y; o2[n][2] = bv2.z; o2[n][3] = bv2.w;
  }
#pragma unroll 8
  for (int k = 0; k < 64; ++k) {
    float2 iA = *(const float2*)&hT[k][n0];
    float2 iB = *(const float2*)&hT[k][n0 + 2];
    float4 w4 = *(const float4*)&WA[k][f0];
    float in[4] = {iA.x, iA.y, iB.x, iB.y};
    float ww[4] = {w4.x, w4.y, w4.z, w4.w};
#pragma unroll
    for (int n = 0; n < 4; ++n)
#pragma unroll
      for (int j = 0; j < 4; ++j) o2[n][j] = fmaf(in[n], ww[j], o2[n][j]);
  }
  __syncthreads();  // GEMM2 reads done; hT reusable as reduce scratch

  float s[4] = {0.f, 0.f, 0.f, 0.f}, q[4] = {0.f, 0.f, 0.f, 0.f};
#pragma unroll
  for (int n = 0; n < 4; ++n) {
    int node = tile0 + n0 + n;
    if (node < NN) {
      float4 v = {o2[n][0], o2[n][1], o2[n][2], o2[n][3]};
      *(float4*)&out[node * 64 + f0] = v;
#pragma unroll
      for (int j = 0; j < 4; ++j) {
        s[j] += o2[n][j];
        q[j] = fmaf(o2[n][j], o2[n][j], q[j]);
      }
    }
  }
  float* red = &hT[0][0];
#pragma unroll
  for (int j = 0; j < 4; ++j) {
    red[(f0 + j) * 16 + ng] = s[j];
    red[1024 + (f0 + j) * 16 + ng] = q[j];
  }
  __syncthreads();
  if (tid < 64) {
    float ss = 0.f, qq = 0.f;
    for (int g = 0; g < 16; ++g) {
      ss += red[tid * 16 + g];
      qq += red[1024 + tid * 16 + g];
    }
    atomicAdd(&sums[tid], ss);
    atomicAdd(&sums[64 + tid], qq);
  }
}

// ---------------- BN finalize + relu, in place on d_out ----------------
__global__ __launch_bounds__(256) void bn_k(float* __restrict__ h2out,
                                            const float* __restrict__ sums,
                                            const float* __restrict__ gamma,
                                            const float* __restrict__ beta) {
  __shared__ float sc[64], sh[64];
  int tid = threadIdx.x;
  if (tid < 64) {
    const float invN = 1.0f / NN;
    float mean = sums[tid] * invN;
    float var = fmaf(-mean, mean, sums[64 + tid] * invN);
    float s = gamma[tid] * rsqrtf(var + BN_EPS_C);
    sc[tid] = s;
    sh[tid] = fmaf(-mean, s, beta[tid]);
  }
  __syncthreads();
  int gid = blockIdx.x * 256 + tid;
  const int tot = NN * 16;
  float4* p = (float4*)h2out;
  for (int i = gid; i < tot; i += gridDim.x * 256) {
    int f0 = (i & 15) * 4;
    float4 v = p[i];
    v.x = fmaxf(fmaf(v.x, sc[f0 + 0], sh[f0 + 0]), 0.f);
    v.y = fmaxf(fmaf(v.y, sc[f0 + 1], sh[f0 + 1]), 0.f);
    v.z = fmaxf(fmaf(v.z, sc[f0 + 2], sh[f0 + 2]), 0.f);
    v.w = fmaxf(fmaf(v.w, sc[f0 + 3], sh[f0 + 3]), 0.f);
    p[i] = v;
  }
}

extern "C" void kernel_launch(void* const* d_in, const int* in_sizes, int n_in,
                              void* d_out, int out_size, void* d_ws, size_t ws_size,
                              hipStream_t stream) {
  const float* x     = (const float*)d_in[0];
  const int*   src   = (const int*)d_in[1];
  const int*   dst   = (const int*)d_in[2];
  const float* ew    = (const float*)d_in[3];
  const float* W1    = (const float*)d_in[4];
  const float* b1    = (const float*)d_in[5];
  const float* W2    = (const float*)d_in[6];
  const float* b2    = (const float*)d_in[7];
  const float* eps   = (const float*)d_in[8];
  const float* gamma = (const float*)d_in[9];
  const float* beta  = (const float*)d_in[10];
  int E = in_sizes[1];

  // ws: counts[NN] | sums[128] | offs[NN] | sorted[E] u32 | xh[NN*64 h] |
  //     yh[NN*64 h] | rank[E] | W1t | W2t    (all segments 16B-aligned)
  int*            counts = (int*)d_ws;
  float*          sums   = (float*)(counts + NN);
  int*            offs   = (int*)(sums + 128);
  unsigned*       sorted = (unsigned*)(offs + NN);
  unsigned short* xh     = (unsigned short*)(sorted + E);
  unsigned short* yh     = xh + (size_t)NN * 64;
  int*            rank   = (int*)(yh + (size_t)NN * 64);
  float*          W1t    = (float*)(rank + E);
  float*          W2t    = W1t + 4096;
  float*          h2     = (float*)d_out;

  int eb8 = (E / 8 + 255) / 256;
  hipMemsetAsync(counts, 0, (size_t)NN * 4 + 128 * 4, stream);  // counts+sums
  prephist_k<<<CONVB + eb8, 256, 0, stream>>>(x, W1, W2, dst, counts, rank,
                                              W1t, W2t, xh, E);
  scan_k<<<NSB, 256, 0, stream>>>(counts, offs);
  sort_k<<<eb8, 256, 0, stream>>>(dst, rank, src, ew, offs, sorted, E);
  gather_k<<<(NN + 31) / 32, 256, 0, stream>>>(xh, sorted, offs, counts, eps, yh);
  mlp_k<<<(NN + 63) / 64, 256, 0, stream>>>(yh, W1t, W2t, b1, b2, h2, sums);
  bn_k<<<3125, 256, 0, stream>>>(h2, sums, gamma, beta);
}

// Round 15
// 140.920 us; speedup vs baseline: 1.2604x; 1.2604x over previous
//
#include <hip/hip_runtime.h>
#include <hip/hip_fp16.h>

#define NN 50000
#define BN_EPS_C 1e-5f
#define SCAN_CHUNK 512
#define NSB ((NN + SCAN_CHUNK - 1) / SCAN_CHUNK)  // 98

__device__ inline unsigned short f2h_bits(float f) {
  __half h = __float2half_rn(f);
  return *reinterpret_cast<unsigned short*>(&h);
}
__device__ inline float h_bits2f(unsigned short b) {
  __half h;
  *reinterpret_cast<unsigned short*>(&h) = b;
  return __half2float(h);
}

// ---------------- prep: zero counts/sums, transpose W1,W2, x -> fp16 ----------
__global__ __launch_bounds__(256) void prep_k(const float* __restrict__ x,
                                              const float* __restrict__ W1,
                                              const float* __restrict__ W2,
                                              int* __restrict__ counts,
                                              float* __restrict__ sums,
                                              float* __restrict__ W1t,
                                              float* __restrict__ W2t,
                                              unsigned short* __restrict__ xh) {
  int gid = blockIdx.x * 256 + threadIdx.x;
  int stride = gridDim.x * 256;
  for (int i = gid; i < NN; i += stride) counts[i] = 0;
  if (gid < 128) sums[gid] = 0.f;
  for (int i = gid; i < 4096; i += stride) {
    int f = i >> 6, k = i & 63;
    W1t[k * 64 + f] = W1[i];  // Wt[k][f] = W[f][k]
    W2t[k * 64 + f] = W2[i];
  }
  const float4* x4 = (const float4*)x;
  uint2* xh2 = (uint2*)xh;
  for (int i = gid; i < NN * 16; i += stride) {
    float4 v = x4[i];
    __half2 h0 = __floats2half2_rn(v.x, v.y);
    __half2 h1 = __floats2half2_rn(v.z, v.w);
    uint2 u;
    u.x = *reinterpret_cast<unsigned*>(&h0);
    u.y = *reinterpret_cast<unsigned*>(&h1);
    xh2[i] = u;
  }
}

// ---------------- histogram of dst + per-edge rank capture ----------------
__global__ __launch_bounds__(256) void histrank_k(const int* __restrict__ dst,
                                                  int* __restrict__ counts,
                                                  int* __restrict__ rank, int E) {
  int t = blockIdx.x * 256 + threadIdx.x;
  int e = t * 4;
  if (e + 3 < E) {
    int4 d = *(const int4*)(dst + e);
    int4 r;
    r.x = atomicAdd(&counts[d.x], 1);
    r.y = atomicAdd(&counts[d.y], 1);
    r.z = atomicAdd(&counts[d.z], 1);
    r.w = atomicAdd(&counts[d.w], 1);
    *(int4*)(rank + e) = r;  // coalesced
  } else {
    for (; e < E; ++e) rank[e] = atomicAdd(&counts[dst[e]], 1);
  }
}

// ---------------- two-level scan: A) block sums ----------------
__global__ __launch_bounds__(256) void scana_k(const int* __restrict__ counts,
                                               int* __restrict__ bsum) {
  __shared__ int red[256];
  int b = blockIdx.x, tid = threadIdx.x;
  int i0 = b * SCAN_CHUNK + tid;
  int v = 0;
  if (i0 < NN) v += counts[i0];
  if (i0 + 256 < NN && tid + 256 < SCAN_CHUNK) v += counts[i0 + 256];
  red[tid] = v;
  __syncthreads();
  for (int s = 128; s > 0; s >>= 1) {
    if (tid < s) red[tid] += red[tid + s];
    __syncthreads();
  }
  if (tid == 0) bsum[b] = red[0];
}

// ---------------- B+C fused: per-block base reduce + local scan -> offs --------
__global__ __launch_bounds__(256) void scanc_k(const int* __restrict__ counts,
                                               const int* __restrict__ bsum,
                                               int* __restrict__ offs) {
  __shared__ int s[256];
  __shared__ int basev;
  int b = blockIdx.x, tid = threadIdx.x;
  s[tid] = (tid < b) ? bsum[tid] : 0;  // NSB=98 <= 256
  __syncthreads();
  for (int st = 128; st > 0; st >>= 1) {
    if (tid < st) s[tid] += s[tid + st];
    __syncthreads();
  }
  if (tid == 0) basev = s[0];
  __syncthreads();
  int base = basev;
  __syncthreads();  // everyone read basev; s reusable
  int i0 = b * SCAN_CHUNK + 2 * tid;
  int c0 = (i0 < NN) ? counts[i0] : 0;
  int c1 = (i0 + 1 < NN) ? counts[i0 + 1] : 0;
  int tsum = c0 + c1;
  s[tid] = tsum;
  __syncthreads();
  for (int off = 1; off < 256; off <<= 1) {
    int t = (tid >= off) ? s[tid - off] : 0;
    __syncthreads();
    s[tid] += t;
    __syncthreads();
  }
  int pre = base + s[tid] - tsum;
  if (i0 < NN) offs[i0] = pre;
  if (i0 + 1 < NN) offs[i0 + 1] = pre + c0;
}

// ---- atomic-free sorted edge build: sorted[offs[d]+rank[e]] = {w:fp16|src:u16} ----
// Plain stores: sorted is 3.2MB -> L2 absorbs the random 4B scatter.
// 8 edges/thread (halved wave count vs 4/thread).
__global__ __launch_bounds__(256) void sort_k(const int* __restrict__ dst,
                                              const int* __restrict__ rank,
                                              const int* __restrict__ srcv,
                                              const float* __restrict__ ew,
                                              const int* __restrict__ offs,
                                              unsigned* __restrict__ sorted, int E) {
  int t = blockIdx.x * 256 + threadIdx.x;
  int e = t * 8;
  if (e + 7 < E) {
    int4 dA = *(const int4*)(dst + e);
    int4 dB = *(const int4*)(dst + e + 4);
    int4 rA = *(const int4*)(rank + e);
    int4 rB = *(const int4*)(rank + e + 4);
    int4 sA = *(const int4*)(srcv + e);
    int4 sB = *(const int4*)(srcv + e + 4);
    float4 wA = *(const float4*)(ew + e);
    float4 wB = *(const float4*)(ew + e + 4);
    sorted[offs[dA.x] + rA.x] = (unsigned)sA.x | ((unsigned)f2h_bits(wA.x) << 16);
    sorted[offs[dA.y] + rA.y] = (unsigned)sA.y | ((unsigned)f2h_bits(wA.y) << 16);
    sorted[offs[dA.z] + rA.z] = (unsigned)sA.z | ((unsigned)f2h_bits(wA.z) << 16);
    sorted[offs[dA.w] + rA.w] = (unsigned)sA.w | ((unsigned)f2h_bits(wA.w) << 16);
    sorted[offs[dB.x] + rB.x] = (unsigned)sB.x | ((unsigned)f2h_bits(wB.x) << 16);
    sorted[offs[dB.y] + rB.y] = (unsigned)sB.y | ((unsigned)f2h_bits(wB.y) << 16);
    sorted[offs[dB.z] + rB.z] = (unsigned)sB.z | ((unsigned)f2h_bits(wB.z) << 16);
    sorted[offs[dB.w] + rB.w] = (unsigned)sB.w | ((unsigned)f2h_bits(wB.w) << 16);
  } else {
    for (; e < E; ++e) {
      unsigned v = (unsigned)srcv[e] | ((unsigned)f2h_bits(ew[e]) << 16);
      sorted[offs[dst[e]] + rank[e]] = v;
    }
  }
}

// ------- fp16 accumulate: 8 halves (uint4) -> 8 f32 accumulators -------
__device__ inline void acc8(float* a, uint4 q, float wgt) {
  float2 f;
  f = __half22float2(*(const __half2*)&q.x);
  a[0] = fmaf(wgt, f.x, a[0]); a[1] = fmaf(wgt, f.y, a[1]);
  f = __half22float2(*(const __half2*)&q.y);
  a[2] = fmaf(wgt, f.x, a[2]); a[3] = fmaf(wgt, f.y, a[3]);
  f = __half22float2(*(const __half2*)&q.z);
  a[4] = fmaf(wgt, f.x, a[4]); a[5] = fmaf(wgt, f.y, a[5]);
  f = __half22float2(*(const __half2*)&q.w);
  a[6] = fmaf(wgt, f.x, a[6]); a[7] = fmaf(wgt, f.y, a[7]);
}

// ------- overflow tail for deg > 64 (rare) -------
__device__ inline void ovf8(float* a, const uint4* __restrict__ xh4,
                            const unsigned* __restrict__ sorted,
                            int off, int cnt, int lane, int es, int fo) {
  for (int b = 64; b < cnt; b += 64) {
    int take = min(64, cnt - b);
    unsigned m = 0;
    if (lane < take) m = sorted[off + b + lane];
    int nb = (take + 7) >> 3;
    for (int t = 0; t < nb; ++t) {
      int i0 = t * 8 + es;
      unsigned v = __shfl((int)m, i0);
      int s = (int)(v & 0xFFFFu);
      float wgt = h_bits2f((unsigned short)(v >> 16));
      uint4 q = xh4[s * 8 + fo];
      acc8(a, q, wgt);
    }
  }
}

// ---------------- gather: y[n] = (1+eps)*xh[n] + sum_e w_e * xh[src_e] --------
// 8 nodes per wave: 8 meta streams, 16 independent 16B gather loads in flight
// per unrolled iteration. es = lane>>3 (8 edge slots), fo = lane&7 (16B octet).
// All register arrays indexed only in fully-unrolled loops (no scratch).
__global__ __launch_bounds__(256) void gather_k(const unsigned short* __restrict__ xh,
                                                const unsigned* __restrict__ sorted,
                                                const int* __restrict__ offs,
                                                const int* __restrict__ counts,
                                                const float* __restrict__ eps,
                                                float* __restrict__ y) {
  __shared__ float stage[4][8][64];  // [wave][node][feat], 8KB
  int tid = threadIdx.x;
  int lane = tid & 63;
  int wv = tid >> 6;
  int es = lane >> 3, fo = lane & 7;
  int nbase = (blockIdx.x * 4 + wv) * 8;
  if (nbase >= NN) return;
  const float c1 = 1.0f + eps[0];
  const uint4* xh4 = (const uint4*)xh;
  const uint2* xh2 = (const uint2*)xh;
  float4* y4 = (float4*)y;

  int offv[8], cntv[8];
  unsigned mv[8];
#pragma unroll
  for (int i = 0; i < 8; ++i) {
    int node = nbase + i;
    bool vld = node < NN;
    offv[i] = vld ? offs[node] : 0;
    cntv[i] = vld ? counts[node] : 0;
  }
#pragma unroll
  for (int i = 0; i < 8; ++i) {
    int tk = min(cntv[i], 64);
    mv[i] = (lane < tk) ? sorted[offv[i] + lane] : 0u;
  }
  float acc[8][8] = {};
  int nbM = 0;
#pragma unroll
  for (int i = 0; i < 8; ++i) nbM = max(nbM, (min(cntv[i], 64) + 7) >> 3);

  for (int t = 0; t < nbM; t += 2) {
    int i0 = t * 8 + es;  // <= 55 (t <= 6)
    int i1 = i0 + 8;      // <= 63; lanes past tk hold m=0 -> w=0
    unsigned e0[8], e1[8];
    uint4 q0[8], q1[8];
#pragma unroll
    for (int i = 0; i < 8; ++i) {
      e0[i] = (unsigned)__shfl((int)mv[i], i0);
      e1[i] = (unsigned)__shfl((int)mv[i], i1);
    }
#pragma unroll
    for (int i = 0; i < 8; ++i) q0[i] = xh4[(int)(e0[i] & 0xFFFFu) * 8 + fo];
#pragma unroll
    for (int i = 0; i < 8; ++i) q1[i] = xh4[(int)(e1[i] & 0xFFFFu) * 8 + fo];
#pragma unroll
    for (int i = 0; i < 8; ++i)
      acc8(acc[i], q0[i], h_bits2f((unsigned short)(e0[i] >> 16)));
#pragma unroll
    for (int i = 0; i < 8; ++i)
      acc8(acc[i], q1[i], h_bits2f((unsigned short)(e1[i] >> 16)));
  }
#pragma unroll
  for (int i = 0; i < 8; ++i)
    if (cntv[i] > 64) ovf8(acc[i], xh4, sorted, offv[i], cntv[i], lane, es, fo);

  // reduce across es (lane bits 3,4,5)
#pragma unroll
  for (int i = 0; i < 8; ++i)
#pragma unroll
    for (int j = 0; j < 8; ++j) {
      acc[i][j] += __shfl_xor(acc[i][j], 8);
      acc[i][j] += __shfl_xor(acc[i][j], 16);
      acc[i][j] += __shfl_xor(acc[i][j], 32);
    }
  // stage: es group i holds node nbase+i's reduced row in its 8 lanes
#pragma unroll
  for (int i = 0; i < 8; ++i) {
    if (es == i) {
      float4 lo = {acc[i][0], acc[i][1], acc[i][2], acc[i][3]};
      float4 hi = {acc[i][4], acc[i][5], acc[i][6], acc[i][7]};
      float* dp = &stage[wv][i][fo * 8];
      *(float4*)dp = lo;
      *(float4*)(dp + 4) = hi;
    }
  }
  __builtin_amdgcn_wave_barrier();  // intra-wave ordering of DS ops
  // dense store: 2KB contiguous per wave (2 float4 per lane), residual fused
#pragma unroll
  for (int h = 0; h < 2; ++h) {
    int node = nbase + h * 4 + (lane >> 4);
    int q = lane & 15;
    if (node < NN) {
      float4 r = *(float4*)&stage[wv][h * 4 + (lane >> 4)][q * 4];
      uint2 xb = xh2[node * 16 + q];
      float2 xlo = __half22float2(*(const __half2*)&xb.x);
      float2 xhi = __half22float2(*(const __half2*)&xb.y);
      r.x = fmaf(c1, xlo.x, r.x); r.y = fmaf(c1, xlo.y, r.y);
      r.z = fmaf(c1, xhi.x, r.z); r.w = fmaf(c1, xhi.y, r.w);
      y4[node * 16 + q] = r;
    }
  }
}

// ---------------- MLP1(relu) + MLP2 + BN partials from y ----------------
__global__ __launch_bounds__(256) void mlp_k(const float* __restrict__ y,
                                             const float* __restrict__ W1t,
                                             const float* __restrict__ W2t,
                                             const float* __restrict__ b1,
                                             const float* __restrict__ b2,
                                             float* __restrict__ out,
                                             float* __restrict__ sums) {
  __shared__ float hT[64][66];   // [k][local node]
  __shared__ float WA[64][64];
  int tid = threadIdx.x;
  int tile0 = blockIdx.x * 64;
  for (int i = tid; i < 4096; i += 256) ((float*)WA)[i] = W1t[i];
  const float4* y4 = (const float4*)y;
  for (int i = tid; i < 1024; i += 256) {
    int nl = i >> 4, fq = i & 15;
    int node = tile0 + nl;
    float4 v = {0, 0, 0, 0};
    if (node < NN) v = y4[node * 16 + fq];
    hT[4 * fq + 0][nl] = v.x; hT[4 * fq + 1][nl] = v.y;
    hT[4 * fq + 2][nl] = v.z; hT[4 * fq + 3][nl] = v.w;
  }
  __syncthreads();

  int fg = tid & 15, ng = tid >> 4;
  int f0 = fg * 4, n0 = ng * 4;
  float4 bv = *(const float4*)(b1 + f0);
  float o[4][4];
#pragma unroll
  for (int n = 0; n < 4; ++n) {
    o[n][0] = bv.x; o[n][1] = bv.y; o[n][2] = bv.z; o[n][3] = bv.w;
  }
#pragma unroll 8
  for (int k = 0; k < 64; ++k) {
    float2 iA = *(const float2*)&hT[k][n0];
    float2 iB = *(const float2*)&hT[k][n0 + 2];
    float4 w4 = *(const float4*)&WA[k][f0];
    float in[4] = {iA.x, iA.y, iB.x, iB.y};
    float ww[4] = {w4.x, w4.y, w4.z, w4.w};
#pragma unroll
    for (int n = 0; n < 4; ++n)
#pragma unroll
      for (int j = 0; j < 4; ++j) o[n][j] = fmaf(in[n], ww[j], o[n][j]);
  }
#pragma unroll
  for (int n = 0; n < 4; ++n)
#pragma unroll
    for (int j = 0; j < 4; ++j) o[n][j] = fmaxf(o[n][j], 0.f);

  __syncthreads();  // all GEMM1 reads done
#pragma unroll
  for (int j = 0; j < 4; ++j) {
    float2 vA = {o[0][j], o[1][j]}, vB = {o[2][j], o[3][j]};
    *(float2*)&hT[f0 + j][n0] = vA;
    *(float2*)&hT[f0 + j][n0 + 2] = vB;
  }
  for (int i = tid; i < 4096; i += 256) ((float*)WA)[i] = W2t[i];
  __syncthreads();

  float4 bv2 = *(const float4*)(b2 + f0);
  float o2[4][4];
#pragma unroll
  for (int n = 0; n < 4; ++n) {
    o2[n][0] = bv2.x; o2[n][1] = bv2.y; o2[n][2] = bv2.z; o2[n][3] = bv2.w;
  }
#pragma unroll 8
  for (int k = 0; k < 64; ++k) {
    float2 iA = *(const float2*)&hT[k][n0];
    float2 iB = *(const float2*)&hT[k][n0 + 2];
    float4 w4 = *(const float4*)&WA[k][f0];
    float in[4] = {iA.x, iA.y, iB.x, iB.y};
    float ww[4] = {w4.x, w4.y, w4.z, w4.w};
#pragma unroll
    for (int n = 0; n < 4; ++n)
#pragma unroll
      for (int j = 0; j < 4; ++j) o2[n][j] = fmaf(in[n], ww[j], o2[n][j]);
  }
  __syncthreads();  // GEMM2 reads done; hT reusable as reduce scratch

  float s[4] = {0.f, 0.f, 0.f, 0.f}, q[4] = {0.f, 0.f, 0.f, 0.f};
#pragma unroll
  for (int n = 0; n < 4; ++n) {
    int node = tile0 + n0 + n;
    if (node < NN) {
      float4 v = {o2[n][0], o2[n][1], o2[n][2], o2[n][3]};
      *(float4*)&out[node * 64 + f0] = v;
#pragma unroll
      for (int j = 0; j < 4; ++j) {
        s[j] += o2[n][j];
        q[j] = fmaf(o2[n][j], o2[n][j], q[j]);
      }
    }
  }
  float* red = &hT[0][0];
#pragma unroll
  for (int j = 0; j < 4; ++j) {
    red[(f0 + j) * 16 + ng] = s[j];
    red[1024 + (f0 + j) * 16 + ng] = q[j];
  }
  __syncthreads();
  if (tid < 64) {
    float ss = 0.f, qq = 0.f;
    for (int g = 0; g < 16; ++g) {
      ss += red[tid * 16 + g];
      qq += red[1024 + tid * 16 + g];
    }
    atomicAdd(&sums[tid], ss);
    atomicAdd(&sums[64 + tid], qq);
  }
}

// ---------------- BN finalize + relu, in place on d_out ----------------
__global__ __launch_bounds__(256) void bn_k(float* __restrict__ h2out,
                                            const float* __restrict__ sums,
                                            const float* __restrict__ gamma,
                                            const float* __restrict__ beta) {
  __shared__ float sc[64], sh[64];
  int tid = threadIdx.x;
  if (tid < 64) {
    const float invN = 1.0f / NN;
    float mean = sums[tid] * invN;
    float var = fmaf(-mean, mean, sums[64 + tid] * invN);
    float s = gamma[tid] * rsqrtf(var + BN_EPS_C);
    sc[tid] = s;
    sh[tid] = fmaf(-mean, s, beta[tid]);
  }
  __syncthreads();
  int gid = blockIdx.x * 256 + tid;
  const int tot = NN * 16;
  float4* p = (float4*)h2out;
  for (int i = gid; i < tot; i += gridDim.x * 256) {
    int f0 = (i & 15) * 4;
    float4 v = p[i];
    v.x = fmaxf(fmaf(v.x, sc[f0 + 0], sh[f0 + 0]), 0.f);
    v.y = fmaxf(fmaf(v.y, sc[f0 + 1], sh[f0 + 1]), 0.f);
    v.z = fmaxf(fmaf(v.z, sc[f0 + 2], sh[f0 + 2]), 0.f);
    v.w = fmaxf(fmaf(v.w, sc[f0 + 3], sh[f0 + 3]), 0.f);
    p[i] = v;
  }
}

extern "C" void kernel_launch(void* const* d_in, const int* in_sizes, int n_in,
                              void* d_out, int out_size, void* d_ws, size_t ws_size,
                              hipStream_t stream) {
  const float* x     = (const float*)d_in[0];
  const int*   src   = (const int*)d_in[1];
  const int*   dst   = (const int*)d_in[2];
  const float* ew    = (const float*)d_in[3];
  const float* W1    = (const float*)d_in[4];
  const float* b1    = (const float*)d_in[5];
  const float* W2    = (const float*)d_in[6];
  const float* b2    = (const float*)d_in[7];
  const float* eps   = (const float*)d_in[8];
  const float* gamma = (const float*)d_in[9];
  const float* beta  = (const float*)d_in[10];
  int E = in_sizes[1];

  // ws: counts[NN] | offs[NN] | sorted[E] u32 | xh[NN*64 halves] |
  //     {rank[E] overlaid by y[NN*64]} | sums[128] | W1t | W2t | bsum
  int*            counts = (int*)d_ws;
  int*            offs   = counts + NN;
  unsigned*       sorted = (unsigned*)(offs + NN);
  unsigned short* xh     = (unsigned short*)(sorted + E);
  float*          y      = (float*)(xh + NN * 64);
  int*            rank   = (int*)y;             // dead before gather writes y
  float*          sums   = y + NN * 64;
  float*          W1t    = sums + 128;
  float*          W2t    = W1t + 4096;
  int*            bsum   = (int*)(W2t + 4096);
  float*          h2     = (float*)d_out;

  int eb4 = (E / 4 + 255) / 256;
  int eb8 = (E / 8 + 255) / 256;
  prep_k<<<512, 256, 0, stream>>>(x, W1, W2, counts, sums, W1t, W2t, xh);
  histrank_k<<<eb4, 256, 0, stream>>>(dst, counts, rank, E);
  scana_k<<<NSB, 256, 0, stream>>>(counts, bsum);
  scanc_k<<<NSB, 256, 0, stream>>>(counts, bsum, offs);
  sort_k<<<eb8, 256, 0, stream>>>(dst, rank, src, ew, offs, sorted, E);
  gather_k<<<(NN + 31) / 32, 256, 0, stream>>>(xh, sorted, offs, counts, eps, y);
  mlp_k<<<(NN + 63) / 64, 256, 0, stream>>>(y, W1t, W2t, b1, b2, h2, sums);
  bn_k<<<3125, 256, 0, stream>>>(h2, sums, gamma, beta);
}